// Round 17
// baseline (127.473 us; speedup 1.0000x reference)
//
#include <hip/hip_runtime.h>

typedef unsigned short u16;
typedef unsigned int   u32;
typedef __bf16 bf16x8 __attribute__((ext_vector_type(8)));
typedef __bf16 bf16x2 __attribute__((ext_vector_type(2)));
typedef float  f32x4  __attribute__((ext_vector_type(4)));

#define B_     2
#define N_     2048
#define DIM_   1024
#define HEADS_ 16
#define DH_    64
#define BH_    (B_*HEADS_)   // 32
#define ROWS_  (B_*N_)       // 4096

__device__ __forceinline__ u16 f2b(float f) {
  union { __bf16 h; u16 u; } v; v.h = (__bf16)f; return v.u;
}
__device__ __forceinline__ u32 pkb(float a, float b) {
  bf16x2 t; t[0] = (__bf16)a; t[1] = (__bf16)b;
  union { bf16x2 v; u32 u; } c; c.v = t; return c.u;
}
__device__ __forceinline__ float b2f(u16 h) {
  union { u32 u; float f; } v; v.u = ((u32)h) << 16;
  return v.f;
}
__device__ __forceinline__ void gload16(const void* g, void* l) {
  __builtin_amdgcn_global_load_lds(
      (const __attribute__((address_space(1))) void*)g,
      (__attribute__((address_space(3))) void*)l, 16, 0, 0);
}
__device__ __forceinline__ f32x4 mfma16(bf16x8 a, bf16x8 b, f32x4 c) {
  return __builtin_amdgcn_mfma_f32_16x16x32_bf16(a, b, c, 0, 0, 0);
}

// ---------------- prep: LN + weight transposes (one launch) ----------------
// blocks [0,4096): LayerNorm row   [4096,7168): wqkv^T   [7168,8192): wout^T
__global__ __launch_bounds__(256) void prep_kernel(
    const float* __restrict__ x, const float* __restrict__ lw,
    const float* __restrict__ lb, const float* __restrict__ wqkv,
    const float* __restrict__ wout, u16* __restrict__ xn,
    u16* __restrict__ wqt, u16* __restrict__ wot) {
  __shared__ float tile[32][33];
  int blk = blockIdx.x, t = threadIdx.x;
  if (blk < 4096) {
    int r = blk;
    const float4* xr = (const float4*)(x + (size_t)r * DIM_);
    float4 v = xr[t];
    float s  = v.x + v.y + v.z + v.w;
    float s2 = v.x*v.x + v.y*v.y + v.z*v.z + v.w*v.w;
    #pragma unroll
    for (int off = 32; off >= 1; off >>= 1) {
      s  += __shfl_down(s, off);
      s2 += __shfl_down(s2, off);
    }
    int w = t >> 6, lane = t & 63;
    if (lane == 0) { tile[0][w] = s; tile[1][w] = s2; }
    __syncthreads();
    if (t == 0) {
      float S = tile[0][0]+tile[0][1]+tile[0][2]+tile[0][3];
      float S2 = tile[1][0]+tile[1][1]+tile[1][2]+tile[1][3];
      float mu = S * (1.0f/DIM_);
      float var = S2 * (1.0f/DIM_) - mu*mu;
      tile[2][0] = mu; tile[2][1] = rsqrtf(var + 1e-5f);
    }
    __syncthreads();
    float mu = tile[2][0], rs = tile[2][1];
    float4 wv = ((const float4*)lw)[t];
    float4 bv = ((const float4*)lb)[t];
    u32 lo = pkb((v.x-mu)*rs*wv.x + bv.x, (v.y-mu)*rs*wv.y + bv.y);
    u32 hi = pkb((v.z-mu)*rs*wv.z + bv.z, (v.w-mu)*rs*wv.w + bv.w);
    ((uint2*)xn)[(size_t)r*256 + t] = make_uint2(lo, hi);
  } else {
    const float* in; u16* outp; int R, C, c0, r0;
    if (blk < 7168) {
      int b2 = blk - 4096;
      in = wqkv; outp = wqt; R = 1024; C = 3072;
      c0 = (b2 % 96) * 32; r0 = (b2 / 96) * 32;
    } else {
      int b2 = blk - 7168;
      in = wout; outp = wot; R = 1024; C = 1024;
      c0 = (b2 & 31) * 32; r0 = (b2 >> 5) * 32;
    }
    int tx = t & 31, ty = t >> 5;
    #pragma unroll
    for (int i = 0; i < 4; i++)
      tile[ty + i*8][tx] = in[(size_t)(r0 + ty + i*8) * C + c0 + tx];
    __syncthreads();
    #pragma unroll
    for (int i = 0; i < 4; i++)
      outp[(size_t)(c0 + ty + i*8) * R + r0 + tx] = f2b(tile[tx][ty + i*8]);
  }
}

// ---------------- QKV GEMM (R13 structure) + XCD-swizzled 1-D grid ---------
// 128x128 tile, BK=32, single-buffer LDS + syncthreads.
// grid 768 = 8 XCDs x 96 contiguous nb each (bijective since 768%8==0).
// Scatter epilogue: q (bh,n,d), k (bh,n,d), v^T (bh,d,n).
__global__ __launch_bounds__(256) void gemm_qkv(
    const u16* __restrict__ A, const u16* __restrict__ Bt,
    u16* __restrict__ qo, u16* __restrict__ ko, u16* __restrict__ vo) {
  const int K = 1024;
  __shared__ __align__(16) u16 lA[128*32];
  __shared__ __align__(16) u16 lB[128*32];
  int tid = threadIdx.x;
  int lane = tid & 63;
  int w = tid >> 6, wm = w >> 1, wn = w & 1;
  int l15 = lane & 15, g = lane >> 4;
  int lin = blockIdx.x;
  int nb = (lin & 7) * 96 + (lin >> 3);
  int bm = nb & 31, bn = nb >> 5;
  const f32x4 z = {0.f, 0.f, 0.f, 0.f};
  f32x4 acc[4][4];
  #pragma unroll
  for (int i = 0; i < 4; i++)
    #pragma unroll
    for (int j = 0; j < 4; j++)
      acc[i][j] = z;
  const u16* ag = A  + (size_t)(bm*128 + (tid>>2)) * K + (tid&3)*8;
  const u16* bg = Bt + (size_t)(bn*128 + (tid>>2)) * K + (tid&3)*8;
  u16* la = lA + tid*8;
  u16* lb = lB + tid*8;
  for (int k0 = 0; k0 < K; k0 += 32) {
    gload16(ag + k0,                la);
    gload16(ag + (size_t)64*K + k0, la + 2048);
    gload16(bg + k0,                lb);
    gload16(bg + (size_t)64*K + k0, lb + 2048);
    __syncthreads();
    bf16x8 af[4], bfr[4];
    #pragma unroll
    for (int mt = 0; mt < 4; mt++)
      af[mt] = *(const bf16x8*)(lA + (wm*64 + mt*16 + l15)*32 + g*8);
    #pragma unroll
    for (int nt = 0; nt < 4; nt++)
      bfr[nt] = *(const bf16x8*)(lB + (wn*64 + nt*16 + l15)*32 + g*8);
    __builtin_amdgcn_s_setprio(1);
    #pragma unroll
    for (int mt = 0; mt < 4; mt++)
      #pragma unroll
      for (int nt = 0; nt < 4; nt++)
        acc[mt][nt] = mfma16(af[mt], bfr[nt], acc[mt][nt]);
    __builtin_amdgcn_s_setprio(0);
    __syncthreads();
  }
  #pragma unroll
  for (int mt = 0; mt < 4; mt++) {
    #pragma unroll
    for (int nt = 0; nt < 4; nt++) {
      #pragma unroll
      for (int reg = 0; reg < 4; reg++) {
        int rr = bm*128 + wm*64 + mt*16 + g*4 + reg;
        int cc = bn*128 + wn*64 + nt*16 + l15;
        float val = acc[mt][nt][reg];
        int which = cc >> 10, inner = cc & 1023;
        int h = inner >> 6, dd = inner & 63;
        int b = rr >> 11, np = rr & 2047;
        int bh = b*HEADS_ + h;
        if (which == 0)      qo[((size_t)(bh*2048 + np))*64 + dd] = f2b(val);
        else if (which == 1) ko[((size_t)(bh*2048 + np))*64 + dd] = f2b(val);
        else                 vo[((size_t)(bh*64 + dd))*2048 + np] = f2b(val);
      }
    }
  }
}

// ---------------- RoPE in-place on k only (bh,n,64); coalesced -------------
// (Q rotation is fused into flash_attn's register Q-load.)
__global__ __launch_bounds__(256) void rope_k_kernel(u16* k) {
  int tid = blockIdx.x * 256 + threadIdx.x;   // 524288 = BH*N*8
  int row = tid >> 3, sub = tid & 7;
  int n = row & 2047;
  u32* kp = (u32*)(k + (size_t)row * 64 + sub * 8);
  uint4 uk = *(uint4*)kp;
  float c4[4], s4[4];
  #pragma unroll
  for (int j = 0; j < 4; j++) {
    int p = sub*4 + j;
    float freq = expf(-(2.0f * (float)p) * (9.210340371976184f / 64.0f));
    float ang = (float)n * freq;
    __sincosf(ang, &s4[j], &c4[j]);
  }
#define ROPE_K(u, c, s) { \
    float e = b2f((u16)(u)), o = b2f((u16)((u) >> 16)); \
    (u) = pkb(e*(c) - o*(s), o*(c) + e*(s)); }
  ROPE_K(uk.x, c4[0], s4[0]) ROPE_K(uk.y, c4[1], s4[1])
  ROPE_K(uk.z, c4[2], s4[2]) ROPE_K(uk.w, c4[3], s4[3])
#undef ROPE_K
  *(uint4*)kp = uk;
}

// ---------------- Output GEMM: 128x64 tile, XCD-swizzled 1-D grid ----------
__global__ __launch_bounds__(256) void gemm_out(
    const u16* __restrict__ A, const u16* __restrict__ Bt,
    const float* __restrict__ bias, float* __restrict__ out) {
  const int K = 1024, N = 1024;
  __shared__ __align__(16) u16 lA[128*32];   // 8KB
  __shared__ __align__(16) u16 lB[64*32];    // 4KB
  int tid = threadIdx.x;
  int lane = tid & 63;
  int w = tid >> 6, wm = w >> 1, wn = w & 1;
  int l15 = lane & 15, g = lane >> 4;
  int lin = blockIdx.x;
  int nb = (lin & 7) * 64 + (lin >> 3);      // 512 = 8*64, bijective
  int bm = nb & 31, bn = nb >> 5;
  const f32x4 z = {0.f, 0.f, 0.f, 0.f};
  f32x4 acc[4][2];
  #pragma unroll
  for (int i = 0; i < 4; i++)
    #pragma unroll
    for (int j = 0; j < 2; j++)
      acc[i][j] = z;
  const u16* ag = A  + (size_t)(bm*128 + (tid>>2)) * K + (tid&3)*8;
  const u16* bg = Bt + (size_t)(bn*64 + (tid>>2)) * K + (tid&3)*8;
  u16* la = lA + tid*8;
  u16* lb = lB + tid*8;
  for (int k0 = 0; k0 < K; k0 += 32) {
    gload16(ag + k0,                la);
    gload16(ag + (size_t)64*K + k0, la + 2048);
    gload16(bg + k0,                lb);
    __syncthreads();
    bf16x8 af[4], bfr[2];
    #pragma unroll
    for (int mt = 0; mt < 4; mt++)
      af[mt] = *(const bf16x8*)(lA + (wm*64 + mt*16 + l15)*32 + g*8);
    #pragma unroll
    for (int nt = 0; nt < 2; nt++)
      bfr[nt] = *(const bf16x8*)(lB + (wn*32 + nt*16 + l15)*32 + g*8);
    __builtin_amdgcn_s_setprio(1);
    #pragma unroll
    for (int mt = 0; mt < 4; mt++)
      #pragma unroll
      for (int nt = 0; nt < 2; nt++)
        acc[mt][nt] = mfma16(af[mt], bfr[nt], acc[mt][nt]);
    __builtin_amdgcn_s_setprio(0);
    __syncthreads();
  }
  #pragma unroll
  for (int mt = 0; mt < 4; mt++)
    #pragma unroll
    for (int nt = 0; nt < 2; nt++)
      #pragma unroll
      for (int reg = 0; reg < 4; reg++) {
        int rr = bm*128 + wm*64 + mt*16 + g*4 + reg;
        int cc = bn*64 + wn*32 + nt*16 + l15;
        out[(size_t)rr * N + cc] = acc[mt][nt][reg] + bias[cc];
      }
}

// ---------------- Flash attention (key-split wave pairs + fused Q-RoPE) -----
__global__ __launch_bounds__(512, 4) void flash_attn(
    const u16* __restrict__ qbf, const u16* __restrict__ kbf,
    const u16* __restrict__ vt, u16* __restrict__ aout) {
  __shared__ __align__(16) char smem[49152];      // 3x8KB K | 3x8KB V; reused
  char* lK = smem;            // lK[buf] at buf*8192
  char* lV = smem + 24576;    // lV[buf] at 24576 + buf*8192
  int tid = threadIdx.x;
  int w = tid >> 6, lane = tid & 63;
  int l15 = lane & 15, g = lane >> 4;
  int p = w & 3, rho = w >> 2;
  int lin = blockIdx.x;
  int nb = (lin & 7) * 64 + (lin >> 3);
  int bh = nb >> 4, qb = nb & 15;
  const f32x4 z = {0.f, 0.f, 0.f, 0.f};
  // Q B-fragments: q = p*32 + qt*16 + l15, d = dh*32 + g*8 .. +7
  // Fused RoPE: rotate pairs in f32 + scale by DH^-1/2*log2(e) at load.
  const u16* qrow_base = qbf + ((size_t)bh*2048 + qb*128 + p*32) * 64;
  const float qs = 0.125f * 1.4426950408889634f;
  bf16x8 Qf[2][2];
  #pragma unroll
  for (int qt = 0; qt < 2; qt++) {
    int n = qb*128 + p*32 + qt*16 + l15;
    #pragma unroll
    for (int dh = 0; dh < 2; dh++) {
      union { bf16x8 v; u32 u[4]; } f;
      f.v = *(const bf16x8*)(qrow_base + (qt*16 + l15)*64 + dh*32 + g*8);
      #pragma unroll
      for (int j = 0; j < 4; j++) {
        int pidx = dh*16 + g*4 + j;
        float freq = expf(-(2.0f * (float)pidx) * (9.210340371976184f / 64.0f));
        float sn, cn;
        __sincosf((float)n * freq, &sn, &cn);
        float e = b2f((u16)f.u[j]), o = b2f((u16)(f.u[j] >> 16));
        f.u[j] = pkb((e*cn - o*sn)*qs, (o*cn + e*sn)*qs);
      }
      Qf[qt][dh] = f.v;
    }
  }
  const char* kb = (const char*)(kbf + (size_t)bh * 2048 * 64);
  const char* vb = (const char*)(vt  + (size_t)bh * 64 * 2048);
  int srow = tid >> 3;                 // LDS row 0..63
  int soff = ((tid & 7) * 16) ^ ((srow & 7) << 4);   // inverse-swizzled source
  // 5-bit kappa within each 32-key half: key = half | (s3s2)<<3 | s4<<2 | s1s0
  int sl = srow & 31;
  int ksrc = (srow & 32) | (((sl >> 2) & 3) << 3) | (((sl >> 4) & 1) << 2) | (sl & 3);
  const int swz = (l15 & 7) << 4;      // row-XOR read swizzle

  float lp[2][2] = {{0.f, 0.f}, {0.f, 0.f}};   // [qt][kt] partial denominators
  f32x4 o[4][2];                               // [dt][qt] partial O^T
  #pragma unroll
  for (int i = 0; i < 4; i++)
    #pragma unroll
    for (int j = 0; j < 2; j++)
      o[i][j] = z;

#define STAGE(t, buf) { \
    gload16(kb + (size_t)((t)*64 + ksrc) * 128 + soff, lK + (buf)*8192 + (size_t)tid*16); \
    gload16(vb + (size_t)srow * 4096 + (t)*128 + soff, lV + (buf)*8192 + (size_t)tid*16); }

  STAGE(0, 0)
  STAGE(1, 1)
  asm volatile("s_waitcnt vmcnt(2)" ::: "memory");
  __builtin_amdgcn_s_barrier();

  int cur = 0, pfb = 2;
  #pragma unroll 1
  for (int t = 0; t < 32; ++t) {
    if (t < 30) STAGE(t + 2, pfb)
    const char* Kc = lK + cur*8192;
    const char* Vc = lV + cur*8192;
    // QK^T over this wave's 32-key half: st[kt][qt]
    f32x4 st[2][2];
    bf16x8 ka[2][2];
    #pragma unroll
    for (int kt = 0; kt < 2; kt++)
      #pragma unroll
      for (int dh = 0; dh < 2; dh++)
        ka[kt][dh] = *(const bf16x8*)(Kc + (rho*32 + kt*16 + l15)*128
                                         + ((dh*64 + g*16) ^ swz));
    __builtin_amdgcn_s_setprio(1);
    #pragma unroll
    for (int kt = 0; kt < 2; kt++)
      #pragma unroll
      for (int qt = 0; qt < 2; qt++) {
        f32x4 a = mfma16(ka[kt][0], Qf[qt][0], z);
        st[kt][qt] = mfma16(ka[kt][1], Qf[qt][1], a);
      }
    __builtin_amdgcn_s_setprio(0);
    // fixed-shift softmax: p = exp2(s); kappa makes lane's keys g*8+kt*4+r
    #pragma unroll
    for (int kt = 0; kt < 2; kt++)
      #pragma unroll
      for (int qt = 0; qt < 2; qt++)
        #pragma unroll
        for (int r = 0; r < 4; r++) {
          float pv = __builtin_amdgcn_exp2f(st[kt][qt][r]);
          st[kt][qt][r] = pv;
          lp[qt][kt] += pv;
        }
    // V fragments for this wave's key half (shared across qt)
    bf16x8 vf[4];
    #pragma unroll
    for (int dt = 0; dt < 4; dt++)
      vf[dt] = *(const bf16x8*)(Vc + (dt*16 + l15)*128 + ((rho*64 + g*16) ^ swz));
    // PV with in-register P
    __builtin_amdgcn_s_setprio(1);
    #pragma unroll
    for (int qt = 0; qt < 2; qt++) {
      union { u32 u[4]; bf16x8 v; } pf;
      pf.u[0] = pkb(st[0][qt][0], st[0][qt][1]);
      pf.u[1] = pkb(st[0][qt][2], st[0][qt][3]);
      pf.u[2] = pkb(st[1][qt][0], st[1][qt][1]);
      pf.u[3] = pkb(st[1][qt][2], st[1][qt][3]);
      #pragma unroll
      for (int dt = 0; dt < 4; dt++)
        o[dt][qt] = mfma16(vf[dt], pf.v, o[dt][qt]);
    }
    __builtin_amdgcn_s_setprio(0);
    if (t < 31) {
      if (t < 30) { asm volatile("s_waitcnt vmcnt(2)" ::: "memory"); }
      else        { asm volatile("s_waitcnt vmcnt(0)" ::: "memory"); }
      __builtin_amdgcn_s_barrier();
    }
    cur = (cur + 1 == 3) ? 0 : cur + 1;
    pfb = (pfb + 1 == 3) ? 0 : pfb + 1;
  }
#undef STAGE

  // wave-local denominator per qt (sum over this wave's 32 keys for q=l15)
  float ls[2];
  #pragma unroll
  for (int qt = 0; qt < 2; qt++) {
    ls[qt] = lp[qt][0] + lp[qt][1];
    ls[qt] += __shfl_xor(ls[qt], 16);
    ls[qt] += __shfl_xor(ls[qt], 32);
  }
  __syncthreads();   // all waves done with K/V buffers

  // pair merge phase 1: upper (rho=1) writes f32 partials + denominators
  float* lspx = (float*)(smem + 32768);   // [p][qt*16+l15]
  if (rho == 1) {
    #pragma unroll
    for (int dt = 0; dt < 4; dt++)
      #pragma unroll
      for (int qt = 0; qt < 2; qt++) {
        int ql = qt*16 + l15;
        int off = p*8192 + ql*256 + ((dt*64 + g*16) ^ ((ql & 7) << 4));
        *(f32x4*)(smem + off) = o[dt][qt];
      }
    if (g == 0) {
      lspx[p*64 + l15]      = ls[0];
      lspx[p*64 + 16 + l15] = ls[1];
    }
  }
  __syncthreads();
  // phase 2: lower (rho=0) reads ALL partner partials into registers
  float rls[2] = {0.f, 0.f};
  if (rho == 0) {
    #pragma unroll
    for (int qt = 0; qt < 2; qt++)
      rls[qt] = 1.0f / (ls[qt] + lspx[p*64 + qt*16 + l15]);
    #pragma unroll
    for (int dt = 0; dt < 4; dt++)
      #pragma unroll
      for (int qt = 0; qt < 2; qt++) {
        int ql = qt*16 + l15;
        int off = p*8192 + ql*256 + ((dt*64 + g*16) ^ ((ql & 7) << 4));
        o[dt][qt] += *(const f32x4*)(smem + off);
      }
  }
  __syncthreads();   // ALL f32 reads complete before bf16 rows overwrite them
  // phase 3: lower waves write normalized bf16 rows [q32][128B]
  if (rho == 0) {
    #pragma unroll
    for (int dt = 0; dt < 4; dt++)
      #pragma unroll
      for (int qt = 0; qt < 2; qt++) {
        int ql = qt*16 + l15;
        u32 w0 = pkb(o[dt][qt][0]*rls[qt], o[dt][qt][1]*rls[qt]);
        u32 w1 = pkb(o[dt][qt][2]*rls[qt], o[dt][qt][3]*rls[qt]);
        int d2 = dt*32 + g*8;   // byte offset of d run (d = dt*16+g*4)
        *(uint2*)(smem + p*8192 + ql*128 + (d2 ^ ((ql & 7) << 4))) =
            make_uint2(w0, w1);
      }
  }
  __syncthreads();
  // output: 128 rows x 128B, 512 threads x 2 uint4
  int row = tid >> 2;
  int b = bh >> 4, h = bh & 15;
  int n = qb*128 + row;
  #pragma unroll
  for (int j = 0; j < 2; j++) {
    int slot = (tid & 3)*2 + j;
    uint4 rv = *(const uint4*)(smem + (row >> 5)*8192 + (row & 31)*128
                               + ((slot*16) ^ ((row & 7) << 4)));
    *(uint4*)(aout + ((size_t)(b*2048 + n))*1024 + h*64 + slot*8) = rv;
  }
}

extern "C" void kernel_launch(void* const* d_in, const int* in_sizes, int n_in,
                              void* d_out, int out_size, void* d_ws, size_t ws_size,
                              hipStream_t stream) {
  const float* x    = (const float*)d_in[0];
  const float* lw   = (const float*)d_in[1];
  const float* lb   = (const float*)d_in[2];
  const float* wqkv = (const float*)d_in[3];
  const float* wout = (const float*)d_in[4];
  const float* bout = (const float*)d_in[5];
  float* out = (float*)d_out;

  char* ws = (char*)d_ws;
  size_t off = 0;
  auto alloc = [&](size_t bytes) {
    char* p = ws + off;
    off += (bytes + 255) & ~(size_t)255;
    return p;
  };
  u16* xn   = (u16*)alloc((size_t)ROWS_*DIM_*2);
  u16* wqt  = (u16*)alloc((size_t)3072*1024*2);
  u16* wot  = (u16*)alloc((size_t)1024*1024*2);
  u16* qb   = (u16*)alloc((size_t)BH_*2048*64*2);
  u16* kb   = (u16*)alloc((size_t)BH_*2048*64*2);
  u16* vtb  = (u16*)alloc((size_t)BH_*2048*64*2);
  u16* aout = (u16*)alloc((size_t)ROWS_*1024*2);

  prep_kernel<<<8192, 256, 0, stream>>>(x, lw, lb, wqkv, wout, xn, wqt, wot);
  gemm_qkv<<<768, 256, 0, stream>>>(xn, wqt, qb, kb, vtb);
  rope_k_kernel<<<2048, 256, 0, stream>>>(kb);
  flash_attn<<<512, 512, 0, stream>>>(qb, kb, vtb, aout);
  gemm_out<<<512, 256, 0, stream>>>(aout, wot, bout, out);
}

// Round 18
// 115.000 us; speedup vs baseline: 1.1085x; 1.1085x over previous
//
#include <hip/hip_runtime.h>

typedef unsigned short u16;
typedef unsigned int   u32;
typedef __bf16 bf16x8 __attribute__((ext_vector_type(8)));
typedef __bf16 bf16x2 __attribute__((ext_vector_type(2)));
typedef float  f32x4  __attribute__((ext_vector_type(4)));

#define B_     2
#define N_     2048
#define DIM_   1024
#define HEADS_ 16
#define DH_    64
#define BH_    (B_*HEADS_)   // 32
#define ROWS_  (B_*N_)       // 4096

__device__ __forceinline__ u16 f2b(float f) {
  union { __bf16 h; u16 u; } v; v.h = (__bf16)f; return v.u;
}
__device__ __forceinline__ u32 pkb(float a, float b) {
  bf16x2 t; t[0] = (__bf16)a; t[1] = (__bf16)b;
  union { bf16x2 v; u32 u; } c; c.v = t; return c.u;
}
__device__ __forceinline__ float b2f(u16 h) {
  union { u32 u; float f; } v; v.u = ((u32)h) << 16;
  return v.f;
}
__device__ __forceinline__ void gload16(const void* g, void* l) {
  __builtin_amdgcn_global_load_lds(
      (const __attribute__((address_space(1))) void*)g,
      (__attribute__((address_space(3))) void*)l, 16, 0, 0);
}
__device__ __forceinline__ f32x4 mfma16(bf16x8 a, bf16x8 b, f32x4 c) {
  return __builtin_amdgcn_mfma_f32_16x16x32_bf16(a, b, c, 0, 0, 0);
}

// ---------------- prep: LN + weight transposes (one launch) ----------------
// blocks [0,4096): LayerNorm row   [4096,7168): wqkv^T   [7168,8192): wout^T
__global__ __launch_bounds__(256) void prep_kernel(
    const float* __restrict__ x, const float* __restrict__ lw,
    const float* __restrict__ lb, const float* __restrict__ wqkv,
    const float* __restrict__ wout, u16* __restrict__ xn,
    u16* __restrict__ wqt, u16* __restrict__ wot) {
  __shared__ float tile[32][33];
  int blk = blockIdx.x, t = threadIdx.x;
  if (blk < 4096) {
    int r = blk;
    const float4* xr = (const float4*)(x + (size_t)r * DIM_);
    float4 v = xr[t];
    float s  = v.x + v.y + v.z + v.w;
    float s2 = v.x*v.x + v.y*v.y + v.z*v.z + v.w*v.w;
    #pragma unroll
    for (int off = 32; off >= 1; off >>= 1) {
      s  += __shfl_down(s, off);
      s2 += __shfl_down(s2, off);
    }
    int w = t >> 6, lane = t & 63;
    if (lane == 0) { tile[0][w] = s; tile[1][w] = s2; }
    __syncthreads();
    if (t == 0) {
      float S = tile[0][0]+tile[0][1]+tile[0][2]+tile[0][3];
      float S2 = tile[1][0]+tile[1][1]+tile[1][2]+tile[1][3];
      float mu = S * (1.0f/DIM_);
      float var = S2 * (1.0f/DIM_) - mu*mu;
      tile[2][0] = mu; tile[2][1] = rsqrtf(var + 1e-5f);
    }
    __syncthreads();
    float mu = tile[2][0], rs = tile[2][1];
    float4 wv = ((const float4*)lw)[t];
    float4 bv = ((const float4*)lb)[t];
    u32 lo = pkb((v.x-mu)*rs*wv.x + bv.x, (v.y-mu)*rs*wv.y + bv.y);
    u32 hi = pkb((v.z-mu)*rs*wv.z + bv.z, (v.w-mu)*rs*wv.w + bv.w);
    ((uint2*)xn)[(size_t)r*256 + t] = make_uint2(lo, hi);
  } else {
    const float* in; u16* outp; int R, C, c0, r0;
    if (blk < 7168) {
      int b2 = blk - 4096;
      in = wqkv; outp = wqt; R = 1024; C = 3072;
      c0 = (b2 % 96) * 32; r0 = (b2 / 96) * 32;
    } else {
      int b2 = blk - 7168;
      in = wout; outp = wot; R = 1024; C = 1024;
      c0 = (b2 & 31) * 32; r0 = (b2 >> 5) * 32;
    }
    int tx = t & 31, ty = t >> 5;
    #pragma unroll
    for (int i = 0; i < 4; i++)
      tile[ty + i*8][tx] = in[(size_t)(r0 + ty + i*8) * C + c0 + tx];
    __syncthreads();
    #pragma unroll
    for (int i = 0; i < 4; i++)
      outp[(size_t)(c0 + ty + i*8) * R + r0 + tx] = f2b(tile[tx][ty + i*8]);
  }
}

// ---------------- QKV GEMM (R13/R16-measured best, 2-D grid) ---------------
// 128x128 tile, BK=32, single-buffer LDS + syncthreads.
// Scatter epilogue: q (bh,n,d), k (bh,n,d), v^T (bh,d,n).
__global__ __launch_bounds__(256) void gemm_qkv(
    const u16* __restrict__ A, const u16* __restrict__ Bt,
    u16* __restrict__ qo, u16* __restrict__ ko, u16* __restrict__ vo) {
  const int K = 1024;
  __shared__ __align__(16) u16 lA[128*32];
  __shared__ __align__(16) u16 lB[128*32];
  int tid = threadIdx.x;
  int lane = tid & 63;
  int w = tid >> 6, wm = w >> 1, wn = w & 1;
  int l15 = lane & 15, g = lane >> 4;
  int bm = blockIdx.x, bn = blockIdx.y;
  const f32x4 z = {0.f, 0.f, 0.f, 0.f};
  f32x4 acc[4][4];
  #pragma unroll
  for (int i = 0; i < 4; i++)
    #pragma unroll
    for (int j = 0; j < 4; j++)
      acc[i][j] = z;
  const u16* ag = A  + (size_t)(bm*128 + (tid>>2)) * K + (tid&3)*8;
  const u16* bg = Bt + (size_t)(bn*128 + (tid>>2)) * K + (tid&3)*8;
  u16* la = lA + tid*8;
  u16* lb = lB + tid*8;
  for (int k0 = 0; k0 < K; k0 += 32) {
    gload16(ag + k0,                la);
    gload16(ag + (size_t)64*K + k0, la + 2048);
    gload16(bg + k0,                lb);
    gload16(bg + (size_t)64*K + k0, lb + 2048);
    __syncthreads();
    bf16x8 af[4], bfr[4];
    #pragma unroll
    for (int mt = 0; mt < 4; mt++)
      af[mt] = *(const bf16x8*)(lA + (wm*64 + mt*16 + l15)*32 + g*8);
    #pragma unroll
    for (int nt = 0; nt < 4; nt++)
      bfr[nt] = *(const bf16x8*)(lB + (wn*64 + nt*16 + l15)*32 + g*8);
    __builtin_amdgcn_s_setprio(1);
    #pragma unroll
    for (int mt = 0; mt < 4; mt++)
      #pragma unroll
      for (int nt = 0; nt < 4; nt++)
        acc[mt][nt] = mfma16(af[mt], bfr[nt], acc[mt][nt]);
    __builtin_amdgcn_s_setprio(0);
    __syncthreads();
  }
  #pragma unroll
  for (int mt = 0; mt < 4; mt++) {
    #pragma unroll
    for (int nt = 0; nt < 4; nt++) {
      #pragma unroll
      for (int reg = 0; reg < 4; reg++) {
        int rr = bm*128 + wm*64 + mt*16 + g*4 + reg;
        int cc = bn*128 + wn*64 + nt*16 + l15;
        float val = acc[mt][nt][reg];
        int which = cc >> 10, inner = cc & 1023;
        int h = inner >> 6, dd = inner & 63;
        int b = rr >> 11, np = rr & 2047;
        int bh = b*HEADS_ + h;
        if (which == 0)      qo[((size_t)(bh*2048 + np))*64 + dd] = f2b(val);
        else if (which == 1) ko[((size_t)(bh*2048 + np))*64 + dd] = f2b(val);
        else                 vo[((size_t)(bh*64 + dd))*2048 + np] = f2b(val);
      }
    }
  }
}

// ---------------- RoPE in-place on k only (bh,n,64); coalesced -------------
// (Q rotation is fused into flash_attn's register Q-load.)
__global__ __launch_bounds__(256) void rope_k_kernel(u16* k) {
  int tid = blockIdx.x * 256 + threadIdx.x;   // 524288 = BH*N*8
  int row = tid >> 3, sub = tid & 7;
  int n = row & 2047;
  u32* kp = (u32*)(k + (size_t)row * 64 + sub * 8);
  uint4 uk = *(uint4*)kp;
  float c4[4], s4[4];
  #pragma unroll
  for (int j = 0; j < 4; j++) {
    int p = sub*4 + j;
    float freq = expf(-(2.0f * (float)p) * (9.210340371976184f / 64.0f));
    float ang = (float)n * freq;
    __sincosf(ang, &s4[j], &c4[j]);
  }
#define ROPE_K(u, c, s) { \
    float e = b2f((u16)(u)), o = b2f((u16)((u) >> 16)); \
    (u) = pkb(e*(c) - o*(s), o*(c) + e*(s)); }
  ROPE_K(uk.x, c4[0], s4[0]) ROPE_K(uk.y, c4[1], s4[1])
  ROPE_K(uk.z, c4[2], s4[2]) ROPE_K(uk.w, c4[3], s4[3])
#undef ROPE_K
  *(uint4*)kp = uk;
}

// ---------------- Output GEMM: 128x64 tile, 2-D grid (R16) -----------------
__global__ __launch_bounds__(256) void gemm_out(
    const u16* __restrict__ A, const u16* __restrict__ Bt,
    const float* __restrict__ bias, float* __restrict__ out) {
  const int K = 1024, N = 1024;
  __shared__ __align__(16) u16 lA[128*32];   // 8KB
  __shared__ __align__(16) u16 lB[64*32];    // 4KB
  int tid = threadIdx.x;
  int lane = tid & 63;
  int w = tid >> 6, wm = w >> 1, wn = w & 1;
  int l15 = lane & 15, g = lane >> 4;
  int bm = blockIdx.x, bn = blockIdx.y;
  const f32x4 z = {0.f, 0.f, 0.f, 0.f};
  f32x4 acc[4][2];
  #pragma unroll
  for (int i = 0; i < 4; i++)
    #pragma unroll
    for (int j = 0; j < 2; j++)
      acc[i][j] = z;
  const u16* ag = A  + (size_t)(bm*128 + (tid>>2)) * K + (tid&3)*8;
  const u16* bg = Bt + (size_t)(bn*64 + (tid>>2)) * K + (tid&3)*8;
  u16* la = lA + tid*8;
  u16* lb = lB + tid*8;
  for (int k0 = 0; k0 < K; k0 += 32) {
    gload16(ag + k0,                la);
    gload16(ag + (size_t)64*K + k0, la + 2048);
    gload16(bg + k0,                lb);
    __syncthreads();
    bf16x8 af[4], bfr[2];
    #pragma unroll
    for (int mt = 0; mt < 4; mt++)
      af[mt] = *(const bf16x8*)(lA + (wm*64 + mt*16 + l15)*32 + g*8);
    #pragma unroll
    for (int nt = 0; nt < 2; nt++)
      bfr[nt] = *(const bf16x8*)(lB + (wn*32 + nt*16 + l15)*32 + g*8);
    __builtin_amdgcn_s_setprio(1);
    #pragma unroll
    for (int mt = 0; mt < 4; mt++)
      #pragma unroll
      for (int nt = 0; nt < 2; nt++)
        acc[mt][nt] = mfma16(af[mt], bfr[nt], acc[mt][nt]);
    __builtin_amdgcn_s_setprio(0);
    __syncthreads();
  }
  #pragma unroll
  for (int mt = 0; mt < 4; mt++)
    #pragma unroll
    for (int nt = 0; nt < 2; nt++)
      #pragma unroll
      for (int reg = 0; reg < 4; reg++) {
        int rr = bm*128 + wm*64 + mt*16 + g*4 + reg;
        int cc = bn*64 + wn*32 + nt*16 + l15;
        out[(size_t)rr * N + cc] = acc[mt][nt][reg] + bias[cc];
      }
}

// ---------------- Flash attention (key-split wave pairs + fused Q-RoPE) -----
__global__ __launch_bounds__(512, 4) void flash_attn(
    const u16* __restrict__ qbf, const u16* __restrict__ kbf,
    const u16* __restrict__ vt, u16* __restrict__ aout) {
  __shared__ __align__(16) char smem[49152];      // 3x8KB K | 3x8KB V; reused
  char* lK = smem;            // lK[buf] at buf*8192
  char* lV = smem + 24576;    // lV[buf] at 24576 + buf*8192
  int tid = threadIdx.x;
  int w = tid >> 6, lane = tid & 63;
  int l15 = lane & 15, g = lane >> 4;
  int p = w & 3, rho = w >> 2;
  int lin = blockIdx.x;
  int nb = (lin & 7) * 64 + (lin >> 3);
  int bh = nb >> 4, qb = nb & 15;
  const f32x4 z = {0.f, 0.f, 0.f, 0.f};
  // Q B-fragments: q = p*32 + qt*16 + l15, d = dh*32 + g*8 .. +7
  // Fused RoPE: rotate pairs in f32 + scale by DH^-1/2*log2(e) at load.
  const u16* qrow_base = qbf + ((size_t)bh*2048 + qb*128 + p*32) * 64;
  const float qs = 0.125f * 1.4426950408889634f;
  bf16x8 Qf[2][2];
  #pragma unroll
  for (int qt = 0; qt < 2; qt++) {
    int n = qb*128 + p*32 + qt*16 + l15;
    #pragma unroll
    for (int dh = 0; dh < 2; dh++) {
      union { bf16x8 v; u32 u[4]; } f;
      f.v = *(const bf16x8*)(qrow_base + (qt*16 + l15)*64 + dh*32 + g*8);
      #pragma unroll
      for (int j = 0; j < 4; j++) {
        int pidx = dh*16 + g*4 + j;
        float freq = expf(-(2.0f * (float)pidx) * (9.210340371976184f / 64.0f));
        float sn, cn;
        __sincosf((float)n * freq, &sn, &cn);
        float e = b2f((u16)f.u[j]), o = b2f((u16)(f.u[j] >> 16));
        f.u[j] = pkb((e*cn - o*sn)*qs, (o*cn + e*sn)*qs);
      }
      Qf[qt][dh] = f.v;
    }
  }
  const char* kb = (const char*)(kbf + (size_t)bh * 2048 * 64);
  const char* vb = (const char*)(vt  + (size_t)bh * 64 * 2048);
  int srow = tid >> 3;                 // LDS row 0..63
  int soff = ((tid & 7) * 16) ^ ((srow & 7) << 4);   // inverse-swizzled source
  // 5-bit kappa within each 32-key half: key = half | (s3s2)<<3 | s4<<2 | s1s0
  int sl = srow & 31;
  int ksrc = (srow & 32) | (((sl >> 2) & 3) << 3) | (((sl >> 4) & 1) << 2) | (sl & 3);
  const int swz = (l15 & 7) << 4;      // row-XOR read swizzle

  float lp[2][2] = {{0.f, 0.f}, {0.f, 0.f}};   // [qt][kt] partial denominators
  f32x4 o[4][2];                               // [dt][qt] partial O^T
  #pragma unroll
  for (int i = 0; i < 4; i++)
    #pragma unroll
    for (int j = 0; j < 2; j++)
      o[i][j] = z;

#define STAGE(t, buf) { \
    gload16(kb + (size_t)((t)*64 + ksrc) * 128 + soff, lK + (buf)*8192 + (size_t)tid*16); \
    gload16(vb + (size_t)srow * 4096 + (t)*128 + soff, lV + (buf)*8192 + (size_t)tid*16); }

  STAGE(0, 0)
  STAGE(1, 1)
  asm volatile("s_waitcnt vmcnt(2)" ::: "memory");
  __builtin_amdgcn_s_barrier();

  int cur = 0, pfb = 2;
  #pragma unroll 1
  for (int t = 0; t < 32; ++t) {
    if (t < 30) STAGE(t + 2, pfb)
    const char* Kc = lK + cur*8192;
    const char* Vc = lV + cur*8192;
    // QK^T over this wave's 32-key half: st[kt][qt]
    f32x4 st[2][2];
    bf16x8 ka[2][2];
    #pragma unroll
    for (int kt = 0; kt < 2; kt++)
      #pragma unroll
      for (int dh = 0; dh < 2; dh++)
        ka[kt][dh] = *(const bf16x8*)(Kc + (rho*32 + kt*16 + l15)*128
                                         + ((dh*64 + g*16) ^ swz));
    __builtin_amdgcn_s_setprio(1);
    #pragma unroll
    for (int kt = 0; kt < 2; kt++)
      #pragma unroll
      for (int qt = 0; qt < 2; qt++) {
        f32x4 a = mfma16(ka[kt][0], Qf[qt][0], z);
        st[kt][qt] = mfma16(ka[kt][1], Qf[qt][1], a);
      }
    __builtin_amdgcn_s_setprio(0);
    // fixed-shift softmax: p = exp2(s); kappa makes lane's keys g*8+kt*4+r
    #pragma unroll
    for (int kt = 0; kt < 2; kt++)
      #pragma unroll
      for (int qt = 0; qt < 2; qt++)
        #pragma unroll
        for (int r = 0; r < 4; r++) {
          float pv = __builtin_amdgcn_exp2f(st[kt][qt][r]);
          st[kt][qt][r] = pv;
          lp[qt][kt] += pv;
        }
    // V fragments for this wave's key half (shared across qt)
    bf16x8 vf[4];
    #pragma unroll
    for (int dt = 0; dt < 4; dt++)
      vf[dt] = *(const bf16x8*)(Vc + (dt*16 + l15)*128 + ((rho*64 + g*16) ^ swz));
    // PV with in-register P
    __builtin_amdgcn_s_setprio(1);
    #pragma unroll
    for (int qt = 0; qt < 2; qt++) {
      union { u32 u[4]; bf16x8 v; } pf;
      pf.u[0] = pkb(st[0][qt][0], st[0][qt][1]);
      pf.u[1] = pkb(st[0][qt][2], st[0][qt][3]);
      pf.u[2] = pkb(st[1][qt][0], st[1][qt][1]);
      pf.u[3] = pkb(st[1][qt][2], st[1][qt][3]);
      #pragma unroll
      for (int dt = 0; dt < 4; dt++)
        o[dt][qt] = mfma16(vf[dt], pf.v, o[dt][qt]);
    }
    __builtin_amdgcn_s_setprio(0);
    if (t < 31) {
      if (t < 30) { asm volatile("s_waitcnt vmcnt(2)" ::: "memory"); }
      else        { asm volatile("s_waitcnt vmcnt(0)" ::: "memory"); }
      __builtin_amdgcn_s_barrier();
    }
    cur = (cur + 1 == 3) ? 0 : cur + 1;
    pfb = (pfb + 1 == 3) ? 0 : pfb + 1;
  }
#undef STAGE

  // wave-local denominator per qt (sum over this wave's 32 keys for q=l15)
  float ls[2];
  #pragma unroll
  for (int qt = 0; qt < 2; qt++) {
    ls[qt] = lp[qt][0] + lp[qt][1];
    ls[qt] += __shfl_xor(ls[qt], 16);
    ls[qt] += __shfl_xor(ls[qt], 32);
  }
  __syncthreads();   // all waves done with K/V buffers

  // pair merge phase 1: upper (rho=1) writes f32 partials + denominators
  float* lspx = (float*)(smem + 32768);   // [p][qt*16+l15]
  if (rho == 1) {
    #pragma unroll
    for (int dt = 0; dt < 4; dt++)
      #pragma unroll
      for (int qt = 0; qt < 2; qt++) {
        int ql = qt*16 + l15;
        int off = p*8192 + ql*256 + ((dt*64 + g*16) ^ ((ql & 7) << 4));
        *(f32x4*)(smem + off) = o[dt][qt];
      }
    if (g == 0) {
      lspx[p*64 + l15]      = ls[0];
      lspx[p*64 + 16 + l15] = ls[1];
    }
  }
  __syncthreads();
  // phase 2: lower (rho=0) reads ALL partner partials into registers
  float rls[2] = {0.f, 0.f};
  if (rho == 0) {
    #pragma unroll
    for (int qt = 0; qt < 2; qt++)
      rls[qt] = 1.0f / (ls[qt] + lspx[p*64 + qt*16 + l15]);
    #pragma unroll
    for (int dt = 0; dt < 4; dt++)
      #pragma unroll
      for (int qt = 0; qt < 2; qt++) {
        int ql = qt*16 + l15;
        int off = p*8192 + ql*256 + ((dt*64 + g*16) ^ ((ql & 7) << 4));
        o[dt][qt] += *(const f32x4*)(smem + off);
      }
  }
  __syncthreads();   // ALL f32 reads complete before bf16 rows overwrite them
  // phase 3: lower waves write normalized bf16 rows [q32][128B]
  if (rho == 0) {
    #pragma unroll
    for (int dt = 0; dt < 4; dt++)
      #pragma unroll
      for (int qt = 0; qt < 2; qt++) {
        int ql = qt*16 + l15;
        u32 w0 = pkb(o[dt][qt][0]*rls[qt], o[dt][qt][1]*rls[qt]);
        u32 w1 = pkb(o[dt][qt][2]*rls[qt], o[dt][qt][3]*rls[qt]);
        int d2 = dt*32 + g*8;   // byte offset of d run (d = dt*16+g*4)
        *(uint2*)(smem + p*8192 + ql*128 + (d2 ^ ((ql & 7) << 4))) =
            make_uint2(w0, w1);
      }
  }
  __syncthreads();
  // output: 128 rows x 128B, 512 threads x 2 uint4
  int row = tid >> 2;
  int b = bh >> 4, h = bh & 15;
  int n = qb*128 + row;
  #pragma unroll
  for (int j = 0; j < 2; j++) {
    int slot = (tid & 3)*2 + j;
    uint4 rv = *(const uint4*)(smem + (row >> 5)*8192 + (row & 31)*128
                               + ((slot*16) ^ ((row & 7) << 4)));
    *(uint4*)(aout + ((size_t)(b*2048 + n))*1024 + h*64 + slot*8) = rv;
  }
}

extern "C" void kernel_launch(void* const* d_in, const int* in_sizes, int n_in,
                              void* d_out, int out_size, void* d_ws, size_t ws_size,
                              hipStream_t stream) {
  const float* x    = (const float*)d_in[0];
  const float* lw   = (const float*)d_in[1];
  const float* lb   = (const float*)d_in[2];
  const float* wqkv = (const float*)d_in[3];
  const float* wout = (const float*)d_in[4];
  const float* bout = (const float*)d_in[5];
  float* out = (float*)d_out;

  char* ws = (char*)d_ws;
  size_t off = 0;
  auto alloc = [&](size_t bytes) {
    char* p = ws + off;
    off += (bytes + 255) & ~(size_t)255;
    return p;
  };
  u16* xn   = (u16*)alloc((size_t)ROWS_*DIM_*2);
  u16* wqt  = (u16*)alloc((size_t)3072*1024*2);
  u16* wot  = (u16*)alloc((size_t)1024*1024*2);
  u16* qb   = (u16*)alloc((size_t)BH_*2048*64*2);
  u16* kb   = (u16*)alloc((size_t)BH_*2048*64*2);
  u16* vtb  = (u16*)alloc((size_t)BH_*2048*64*2);
  u16* aout = (u16*)alloc((size_t)ROWS_*1024*2);

  prep_kernel<<<8192, 256, 0, stream>>>(x, lw, lb, wqkv, wout, xn, wqt, wot);
  gemm_qkv<<<dim3(32, 24), 256, 0, stream>>>(xn, wqt, qb, kb, vtb);
  rope_k_kernel<<<2048, 256, 0, stream>>>(kb);
  flash_attn<<<512, 512, 0, stream>>>(qb, kb, vtb, aout);
  gemm_out<<<dim3(32, 16), 256, 0, stream>>>(aout, wot, bout, out);
}

// Round 19
// 111.878 us; speedup vs baseline: 1.1394x; 1.0279x over previous
//
#include <hip/hip_runtime.h>

typedef unsigned short u16;
typedef unsigned int   u32;
typedef __bf16 bf16x8 __attribute__((ext_vector_type(8)));
typedef __bf16 bf16x2 __attribute__((ext_vector_type(2)));
typedef float  f32x4  __attribute__((ext_vector_type(4)));

#define B_     2
#define N_     2048
#define DIM_   1024
#define HEADS_ 16
#define DH_    64
#define BH_    (B_*HEADS_)   // 32
#define ROWS_  (B_*N_)       // 4096

__device__ __forceinline__ u16 f2b(float f) {
  union { __bf16 h; u16 u; } v; v.h = (__bf16)f; return v.u;
}
__device__ __forceinline__ u32 pkb(float a, float b) {
  bf16x2 t; t[0] = (__bf16)a; t[1] = (__bf16)b;
  union { bf16x2 v; u32 u; } c; c.v = t; return c.u;
}
__device__ __forceinline__ float b2f(u16 h) {
  union { u32 u; float f; } v; v.u = ((u32)h) << 16;
  return v.f;
}
__device__ __forceinline__ void gload16(const void* g, void* l) {
  __builtin_amdgcn_global_load_lds(
      (const __attribute__((address_space(1))) void*)g,
      (__attribute__((address_space(3))) void*)l, 16, 0, 0);
}
__device__ __forceinline__ f32x4 mfma16(bf16x8 a, bf16x8 b, f32x4 c) {
  return __builtin_amdgcn_mfma_f32_16x16x32_bf16(a, b, c, 0, 0, 0);
}

// ---------------- prep: LN + weight transposes (one launch) ----------------
// blocks [0,4096): LayerNorm row   [4096,7168): wqkv^T   [7168,8192): wout^T
__global__ __launch_bounds__(256) void prep_kernel(
    const float* __restrict__ x, const float* __restrict__ lw,
    const float* __restrict__ lb, const float* __restrict__ wqkv,
    const float* __restrict__ wout, u16* __restrict__ xn,
    u16* __restrict__ wqt, u16* __restrict__ wot) {
  __shared__ float tile[32][33];
  int blk = blockIdx.x, t = threadIdx.x;
  if (blk < 4096) {
    int r = blk;
    const float4* xr = (const float4*)(x + (size_t)r * DIM_);
    float4 v = xr[t];
    float s  = v.x + v.y + v.z + v.w;
    float s2 = v.x*v.x + v.y*v.y + v.z*v.z + v.w*v.w;
    #pragma unroll
    for (int off = 32; off >= 1; off >>= 1) {
      s  += __shfl_down(s, off);
      s2 += __shfl_down(s2, off);
    }
    int w = t >> 6, lane = t & 63;
    if (lane == 0) { tile[0][w] = s; tile[1][w] = s2; }
    __syncthreads();
    if (t == 0) {
      float S = tile[0][0]+tile[0][1]+tile[0][2]+tile[0][3];
      float S2 = tile[1][0]+tile[1][1]+tile[1][2]+tile[1][3];
      float mu = S * (1.0f/DIM_);
      float var = S2 * (1.0f/DIM_) - mu*mu;
      tile[2][0] = mu; tile[2][1] = rsqrtf(var + 1e-5f);
    }
    __syncthreads();
    float mu = tile[2][0], rs = tile[2][1];
    float4 wv = ((const float4*)lw)[t];
    float4 bv = ((const float4*)lb)[t];
    u32 lo = pkb((v.x-mu)*rs*wv.x + bv.x, (v.y-mu)*rs*wv.y + bv.y);
    u32 hi = pkb((v.z-mu)*rs*wv.z + bv.z, (v.w-mu)*rs*wv.w + bv.w);
    ((uint2*)xn)[(size_t)r*256 + t] = make_uint2(lo, hi);
  } else {
    const float* in; u16* outp; int R, C, c0, r0;
    if (blk < 7168) {
      int b2 = blk - 4096;
      in = wqkv; outp = wqt; R = 1024; C = 3072;
      c0 = (b2 % 96) * 32; r0 = (b2 / 96) * 32;
    } else {
      int b2 = blk - 7168;
      in = wout; outp = wot; R = 1024; C = 1024;
      c0 = (b2 & 31) * 32; r0 = (b2 >> 5) * 32;
    }
    int tx = t & 31, ty = t >> 5;
    #pragma unroll
    for (int i = 0; i < 4; i++)
      tile[ty + i*8][tx] = in[(size_t)(r0 + ty + i*8) * C + c0 + tx];
    __syncthreads();
    #pragma unroll
    for (int i = 0; i < 4; i++)
      outp[(size_t)(c0 + ty + i*8) * R + r0 + tx] = f2b(tile[tx][ty + i*8]);
  }
}

// ---------------- QKV GEMM (measured best, 2-D grid) -----------------------
// 128x128 tile, BK=32, single-buffer LDS + syncthreads.
// Scatter epilogue: q (bh,n,d), k (bh,n,d), v^T (bh,d,n).
__global__ __launch_bounds__(256) void gemm_qkv(
    const u16* __restrict__ A, const u16* __restrict__ Bt,
    u16* __restrict__ qo, u16* __restrict__ ko, u16* __restrict__ vo) {
  const int K = 1024;
  __shared__ __align__(16) u16 lA[128*32];
  __shared__ __align__(16) u16 lB[128*32];
  int tid = threadIdx.x;
  int lane = tid & 63;
  int w = tid >> 6, wm = w >> 1, wn = w & 1;
  int l15 = lane & 15, g = lane >> 4;
  int bm = blockIdx.x, bn = blockIdx.y;
  const f32x4 z = {0.f, 0.f, 0.f, 0.f};
  f32x4 acc[4][4];
  #pragma unroll
  for (int i = 0; i < 4; i++)
    #pragma unroll
    for (int j = 0; j < 4; j++)
      acc[i][j] = z;
  const u16* ag = A  + (size_t)(bm*128 + (tid>>2)) * K + (tid&3)*8;
  const u16* bg = Bt + (size_t)(bn*128 + (tid>>2)) * K + (tid&3)*8;
  u16* la = lA + tid*8;
  u16* lb = lB + tid*8;
  for (int k0 = 0; k0 < K; k0 += 32) {
    gload16(ag + k0,                la);
    gload16(ag + (size_t)64*K + k0, la + 2048);
    gload16(bg + k0,                lb);
    gload16(bg + (size_t)64*K + k0, lb + 2048);
    __syncthreads();
    bf16x8 af[4], bfr[4];
    #pragma unroll
    for (int mt = 0; mt < 4; mt++)
      af[mt] = *(const bf16x8*)(lA + (wm*64 + mt*16 + l15)*32 + g*8);
    #pragma unroll
    for (int nt = 0; nt < 4; nt++)
      bfr[nt] = *(const bf16x8*)(lB + (wn*64 + nt*16 + l15)*32 + g*8);
    __builtin_amdgcn_s_setprio(1);
    #pragma unroll
    for (int mt = 0; mt < 4; mt++)
      #pragma unroll
      for (int nt = 0; nt < 4; nt++)
        acc[mt][nt] = mfma16(af[mt], bfr[nt], acc[mt][nt]);
    __builtin_amdgcn_s_setprio(0);
    __syncthreads();
  }
  #pragma unroll
  for (int mt = 0; mt < 4; mt++) {
    #pragma unroll
    for (int nt = 0; nt < 4; nt++) {
      #pragma unroll
      for (int reg = 0; reg < 4; reg++) {
        int rr = bm*128 + wm*64 + mt*16 + g*4 + reg;
        int cc = bn*128 + wn*64 + nt*16 + l15;
        float val = acc[mt][nt][reg];
        int which = cc >> 10, inner = cc & 1023;
        int h = inner >> 6, dd = inner & 63;
        int b = rr >> 11, np = rr & 2047;
        int bh = b*HEADS_ + h;
        if (which == 0)      qo[((size_t)(bh*2048 + np))*64 + dd] = f2b(val);
        else if (which == 1) ko[((size_t)(bh*2048 + np))*64 + dd] = f2b(val);
        else                 vo[((size_t)(bh*64 + dd))*2048 + np] = f2b(val);
      }
    }
  }
}

// ---------------- RoPE in-place on k only (bh,n,64); coalesced -------------
// (Q rotation is fused into flash_attn's register Q-load.)
__global__ __launch_bounds__(256) void rope_k_kernel(u16* k) {
  int tid = blockIdx.x * 256 + threadIdx.x;   // 524288 = BH*N*8
  int row = tid >> 3, sub = tid & 7;
  int n = row & 2047;
  u32* kp = (u32*)(k + (size_t)row * 64 + sub * 8);
  uint4 uk = *(uint4*)kp;
  float c4[4], s4[4];
  #pragma unroll
  for (int j = 0; j < 4; j++) {
    int p = sub*4 + j;
    float freq = expf(-(2.0f * (float)p) * (9.210340371976184f / 64.0f));
    float ang = (float)n * freq;
    __sincosf(ang, &s4[j], &c4[j]);
  }
#define ROPE_K(u, c, s) { \
    float e = b2f((u16)(u)), o = b2f((u16)((u) >> 16)); \
    (u) = pkb(e*(c) - o*(s), o*(c) + e*(s)); }
  ROPE_K(uk.x, c4[0], s4[0]) ROPE_K(uk.y, c4[1], s4[1])
  ROPE_K(uk.z, c4[2], s4[2]) ROPE_K(uk.w, c4[3], s4[3])
#undef ROPE_K
  *(uint4*)kp = uk;
}

// ---------------- Output GEMM: 128x64 tile, 2-D grid -----------------------
__global__ __launch_bounds__(256) void gemm_out(
    const u16* __restrict__ A, const u16* __restrict__ Bt,
    const float* __restrict__ bias, float* __restrict__ out) {
  const int K = 1024, N = 1024;
  __shared__ __align__(16) u16 lA[128*32];   // 8KB
  __shared__ __align__(16) u16 lB[64*32];    // 4KB
  int tid = threadIdx.x;
  int lane = tid & 63;
  int w = tid >> 6, wm = w >> 1, wn = w & 1;
  int l15 = lane & 15, g = lane >> 4;
  int bm = blockIdx.x, bn = blockIdx.y;
  const f32x4 z = {0.f, 0.f, 0.f, 0.f};
  f32x4 acc[4][2];
  #pragma unroll
  for (int i = 0; i < 4; i++)
    #pragma unroll
    for (int j = 0; j < 2; j++)
      acc[i][j] = z;
  const u16* ag = A  + (size_t)(bm*128 + (tid>>2)) * K + (tid&3)*8;
  const u16* bg = Bt + (size_t)(bn*64 + (tid>>2)) * K + (tid&3)*8;
  u16* la = lA + tid*8;
  u16* lb = lB + tid*8;
  for (int k0 = 0; k0 < K; k0 += 32) {
    gload16(ag + k0,                la);
    gload16(ag + (size_t)64*K + k0, la + 2048);
    gload16(bg + k0,                lb);
    __syncthreads();
    bf16x8 af[4], bfr[2];
    #pragma unroll
    for (int mt = 0; mt < 4; mt++)
      af[mt] = *(const bf16x8*)(lA + (wm*64 + mt*16 + l15)*32 + g*8);
    #pragma unroll
    for (int nt = 0; nt < 2; nt++)
      bfr[nt] = *(const bf16x8*)(lB + (wn*32 + nt*16 + l15)*32 + g*8);
    __builtin_amdgcn_s_setprio(1);
    #pragma unroll
    for (int mt = 0; mt < 4; mt++)
      #pragma unroll
      for (int nt = 0; nt < 2; nt++)
        acc[mt][nt] = mfma16(af[mt], bfr[nt], acc[mt][nt]);
    __builtin_amdgcn_s_setprio(0);
    __syncthreads();
  }
  #pragma unroll
  for (int mt = 0; mt < 4; mt++)
    #pragma unroll
    for (int nt = 0; nt < 2; nt++)
      #pragma unroll
      for (int reg = 0; reg < 4; reg++) {
        int rr = bm*128 + wm*64 + mt*16 + g*4 + reg;
        int cc = bn*64 + wn*32 + nt*16 + l15;
        out[(size_t)rr * N + cc] = acc[mt][nt][reg] + bias[cc];
      }
}

// ---------------- Flash attention (key-split, unrolled x3, MFMA denom) ------
// grid 512 (1-D, XCD-swizzled), 8 waves: wave (p=w&3, rho=w>>2) handles
// q rows [p*32,+32) x keys [rho*32,+32) per KBLK=64 tile. 3-buffer LDS with
// COMPILE-TIME buffer indices (manual 3x unroll) + precomputed per-lane
// offsets -> near-zero per-iter address VALU. Fixed-shift softmax (m=0,
// log2 domain); denominator via ones-MFMA (no VALU adds, no shfl reduce).
// In-register P via 5-bit kappa key-permutation at K staging. Fused Q-RoPE.
__global__ __launch_bounds__(512, 4) void flash_attn(
    const u16* __restrict__ qbf, const u16* __restrict__ kbf,
    const u16* __restrict__ vt, u16* __restrict__ aout) {
  __shared__ __align__(16) char smem[49152];      // 3x8KB K | 3x8KB V; reused
  int tid = threadIdx.x;
  int w = tid >> 6, lane = tid & 63;
  int l15 = lane & 15, g = lane >> 4;
  int p = w & 3, rho = w >> 2;
  int lin = blockIdx.x;
  int nb = (lin & 7) * 64 + (lin >> 3);
  int bh = nb >> 4, qb = nb & 15;
  const f32x4 z = {0.f, 0.f, 0.f, 0.f};
  // Q B-fragments with fused RoPE + DH^-1/2*log2(e) scale.
  const u16* qrow_base = qbf + ((size_t)bh*2048 + qb*128 + p*32) * 64;
  const float qs = 0.125f * 1.4426950408889634f;
  bf16x8 Qf[2][2];
  #pragma unroll
  for (int qt = 0; qt < 2; qt++) {
    int n = qb*128 + p*32 + qt*16 + l15;
    #pragma unroll
    for (int dh = 0; dh < 2; dh++) {
      union { bf16x8 v; u32 u[4]; } f;
      f.v = *(const bf16x8*)(qrow_base + (qt*16 + l15)*64 + dh*32 + g*8);
      #pragma unroll
      for (int j = 0; j < 4; j++) {
        int pidx = dh*16 + g*4 + j;
        float freq = expf(-(2.0f * (float)pidx) * (9.210340371976184f / 64.0f));
        float sn, cn;
        __sincosf((float)n * freq, &sn, &cn);
        float e = b2f((u16)f.u[j]), o = b2f((u16)(f.u[j] >> 16));
        f.u[j] = pkb((e*cn - o*sn)*qs, (o*cn + e*sn)*qs);
      }
      Qf[qt][dh] = f.v;
    }
  }
  const char* kb = (const char*)(kbf + (size_t)bh * 2048 * 64);
  const char* vb = (const char*)(vt  + (size_t)bh * 64 * 2048);
  int srow = tid >> 3;                 // LDS row 0..63
  int soff = ((tid & 7) * 16) ^ ((srow & 7) << 4);   // inverse-swizzled source
  int sl = srow & 31;
  int ksrc = (srow & 32) | (((sl >> 2) & 3) << 3) | (((sl >> 4) & 1) << 2) | (sl & 3);
  const int swz = (l15 & 7) << 4;      // row-XOR read swizzle

  // precomputed per-lane offsets (loop-invariant)
  const size_t kgo = (size_t)ksrc * 128 + soff;     // K global, + t*8192
  const size_t vgo = (size_t)srow * 4096 + soff;    // V global, + t*128
  const int ldk = tid * 16;                          // K LDS dest, + buf*8192
  const int ldv = 24576 + tid * 16;                  // V LDS dest, + buf*8192
  int koff[2][2], voff[4];
  #pragma unroll
  for (int kt = 0; kt < 2; kt++)
    #pragma unroll
    for (int dh = 0; dh < 2; dh++)
      koff[kt][dh] = (rho*32 + kt*16 + l15)*128 + ((dh*64 + g*16) ^ swz);
  #pragma unroll
  for (int dt = 0; dt < 4; dt++)
    voff[dt] = 24576 + (dt*16 + l15)*128 + ((rho*64 + g*16) ^ swz);

  bf16x8 ones;
  #pragma unroll
  for (int i = 0; i < 8; i++) ones[i] = (__bf16)1.0f;

  f32x4 den[2] = {z, z};               // denominator accumulators (ones-MFMA)
  f32x4 o[4][2];                       // [dt][qt] partial O^T
  #pragma unroll
  for (int i = 0; i < 4; i++)
    #pragma unroll
    for (int j = 0; j < 2; j++)
      o[i][j] = z;

#define STAGE(T, BUF) { \
    gload16(kb + (size_t)(T)*8192 + kgo, smem + (BUF)*8192 + ldk); \
    gload16(vb + (size_t)(T)*128  + vgo, smem + (BUF)*8192 + ldv); }

// WM: 2 = vmcnt(2)+barrier, 0 = vmcnt(0)+barrier, 3 = none
#define FBODY(T, CUR, PFB, DOSTAGE, WM) { \
    if (DOSTAGE) STAGE((T) + 2, PFB) \
    f32x4 st[2][2]; \
    bf16x8 ka[2][2]; \
    _Pragma("unroll") \
    for (int kt = 0; kt < 2; kt++) \
      _Pragma("unroll") \
      for (int dh = 0; dh < 2; dh++) \
        ka[kt][dh] = *(const bf16x8*)(smem + (CUR)*8192 + koff[kt][dh]); \
    __builtin_amdgcn_s_setprio(1); \
    _Pragma("unroll") \
    for (int kt = 0; kt < 2; kt++) \
      _Pragma("unroll") \
      for (int qt = 0; qt < 2; qt++) { \
        f32x4 a = mfma16(ka[kt][0], Qf[qt][0], z); \
        st[kt][qt] = mfma16(ka[kt][1], Qf[qt][1], a); \
      } \
    __builtin_amdgcn_s_setprio(0); \
    _Pragma("unroll") \
    for (int kt = 0; kt < 2; kt++) \
      _Pragma("unroll") \
      for (int qt = 0; qt < 2; qt++) \
        _Pragma("unroll") \
        for (int r = 0; r < 4; r++) \
          st[kt][qt][r] = __builtin_amdgcn_exp2f(st[kt][qt][r]); \
    bf16x8 vf[4]; \
    _Pragma("unroll") \
    for (int dt = 0; dt < 4; dt++) \
      vf[dt] = *(const bf16x8*)(smem + (CUR)*8192 + voff[dt]); \
    __builtin_amdgcn_s_setprio(1); \
    _Pragma("unroll") \
    for (int qt = 0; qt < 2; qt++) { \
      union { u32 u[4]; bf16x8 v; } pf; \
      pf.u[0] = pkb(st[0][qt][0], st[0][qt][1]); \
      pf.u[1] = pkb(st[0][qt][2], st[0][qt][3]); \
      pf.u[2] = pkb(st[1][qt][0], st[1][qt][1]); \
      pf.u[3] = pkb(st[1][qt][2], st[1][qt][3]); \
      den[qt] = mfma16(ones, pf.v, den[qt]); \
      _Pragma("unroll") \
      for (int dt = 0; dt < 4; dt++) \
        o[dt][qt] = mfma16(vf[dt], pf.v, o[dt][qt]); \
    } \
    __builtin_amdgcn_s_setprio(0); \
    if ((WM) == 2) { \
      asm volatile("s_waitcnt vmcnt(2)" ::: "memory"); \
      __builtin_amdgcn_s_barrier(); \
    } else if ((WM) == 0) { \
      asm volatile("s_waitcnt vmcnt(0)" ::: "memory"); \
      __builtin_amdgcn_s_barrier(); \
    } }

  // prologue: fill buffers 0 and 1
  STAGE(0, 0)
  STAGE(1, 1)
  asm volatile("s_waitcnt vmcnt(2)" ::: "memory");
  __builtin_amdgcn_s_barrier();

  #pragma unroll 1
  for (int tb = 0; tb < 30; tb += 3) {
    FBODY(tb + 0, 0, 2, 1, 2)
    FBODY(tb + 1, 1, 0, 1, 2)
    FBODY(tb + 2, 2, 1, 1, 2)
  }
  FBODY(30, 0, 0, 0, 0)
  FBODY(31, 1, 0, 0, 3)
#undef STAGE
#undef FBODY

  // wave-local denominator per qt: every reg/lane-row of den holds the full
  // 32-key sum for q = l15 (ones-MFMA column sums) -> no shuffles needed.
  float ls[2] = {den[0][0], den[1][0]};
  __syncthreads();   // all waves done with K/V buffers

  // pair merge phase 1: upper (rho=1) writes f32 partials + denominators
  float* lspx = (float*)(smem + 32768);   // [p][qt*16+l15]
  if (rho == 1) {
    #pragma unroll
    for (int dt = 0; dt < 4; dt++)
      #pragma unroll
      for (int qt = 0; qt < 2; qt++) {
        int ql = qt*16 + l15;
        int off = p*8192 + ql*256 + ((dt*64 + g*16) ^ ((ql & 7) << 4));
        *(f32x4*)(smem + off) = o[dt][qt];
      }
    if (g == 0) {
      lspx[p*64 + l15]      = ls[0];
      lspx[p*64 + 16 + l15] = ls[1];
    }
  }
  __syncthreads();
  // phase 2: lower (rho=0) reads ALL partner partials into registers
  float rls[2] = {0.f, 0.f};
  if (rho == 0) {
    #pragma unroll
    for (int qt = 0; qt < 2; qt++)
      rls[qt] = 1.0f / (ls[qt] + lspx[p*64 + qt*16 + l15]);
    #pragma unroll
    for (int dt = 0; dt < 4; dt++)
      #pragma unroll
      for (int qt = 0; qt < 2; qt++) {
        int ql = qt*16 + l15;
        int off = p*8192 + ql*256 + ((dt*64 + g*16) ^ ((ql & 7) << 4));
        o[dt][qt] += *(const f32x4*)(smem + off);
      }
  }
  __syncthreads();   // ALL f32 reads complete before bf16 rows overwrite them
  // phase 3: lower waves write normalized bf16 rows [q32][128B]
  if (rho == 0) {
    #pragma unroll
    for (int dt = 0; dt < 4; dt++)
      #pragma unroll
      for (int qt = 0; qt < 2; qt++) {
        int ql = qt*16 + l15;
        u32 w0 = pkb(o[dt][qt][0]*rls[qt], o[dt][qt][1]*rls[qt]);
        u32 w1 = pkb(o[dt][qt][2]*rls[qt], o[dt][qt][3]*rls[qt]);
        int d2 = dt*32 + g*8;   // byte offset of d run (d = dt*16+g*4)
        *(uint2*)(smem + p*8192 + ql*128 + (d2 ^ ((ql & 7) << 4))) =
            make_uint2(w0, w1);
      }
  }
  __syncthreads();
  // output: 128 rows x 128B, 512 threads x 2 uint4
  int row = tid >> 2;
  int b = bh >> 4, h = bh & 15;
  int n = qb*128 + row;
  #pragma unroll
  for (int j = 0; j < 2; j++) {
    int slot = (tid & 3)*2 + j;
    uint4 rv = *(const uint4*)(smem + (row >> 5)*8192 + (row & 31)*128
                               + ((slot*16) ^ ((row & 7) << 4)));
    *(uint4*)(aout + ((size_t)(b*2048 + n))*1024 + h*64 + slot*8) = rv;
  }
}

extern "C" void kernel_launch(void* const* d_in, const int* in_sizes, int n_in,
                              void* d_out, int out_size, void* d_ws, size_t ws_size,
                              hipStream_t stream) {
  const float* x    = (const float*)d_in[0];
  const float* lw   = (const float*)d_in[1];
  const float* lb   = (const float*)d_in[2];
  const float* wqkv = (const float*)d_in[3];
  const float* wout = (const float*)d_in[4];
  const float* bout = (const float*)d_in[5];
  float* out = (float*)d_out;

  char* ws = (char*)d_ws;
  size_t off = 0;
  auto alloc = [&](size_t bytes) {
    char* p = ws + off;
    off += (bytes + 255) & ~(size_t)255;
    return p;
  };
  u16* xn   = (u16*)alloc((size_t)ROWS_*DIM_*2);
  u16* wqt  = (u16*)alloc((size_t)3072*1024*2);
  u16* wot  = (u16*)alloc((size_t)1024*1024*2);
  u16* qb   = (u16*)alloc((size_t)BH_*2048*64*2);
  u16* kb   = (u16*)alloc((size_t)BH_*2048*64*2);
  u16* vtb  = (u16*)alloc((size_t)BH_*2048*64*2);
  u16* aout = (u16*)alloc((size_t)ROWS_*1024*2);

  prep_kernel<<<8192, 256, 0, stream>>>(x, lw, lb, wqkv, wout, xn, wqt, wot);
  gemm_qkv<<<dim3(32, 24), 256, 0, stream>>>(xn, wqt, qb, kb, vtb);
  rope_k_kernel<<<2048, 256, 0, stream>>>(kb);
  flash_attn<<<512, 512, 0, stream>>>(qb, kb, vtb, aout);
  gemm_out<<<dim3(32, 16), 256, 0, stream>>>(aout, wot, bout, out);
}

// Round 20
// 110.453 us; speedup vs baseline: 1.1541x; 1.0129x over previous
//
#include <hip/hip_runtime.h>

typedef unsigned short u16;
typedef unsigned int   u32;
typedef __bf16 bf16x8 __attribute__((ext_vector_type(8)));
typedef __bf16 bf16x2 __attribute__((ext_vector_type(2)));
typedef float  f32x4  __attribute__((ext_vector_type(4)));

#define B_     2
#define N_     2048
#define DIM_   1024
#define HEADS_ 16
#define DH_    64
#define BH_    (B_*HEADS_)   // 32
#define ROWS_  (B_*N_)       // 4096

__device__ __forceinline__ u16 f2b(float f) {
  union { __bf16 h; u16 u; } v; v.h = (__bf16)f; return v.u;
}
__device__ __forceinline__ u32 pkb(float a, float b) {
  bf16x2 t; t[0] = (__bf16)a; t[1] = (__bf16)b;
  union { bf16x2 v; u32 u; } c; c.v = t; return c.u;
}
__device__ __forceinline__ float b2f(u16 h) {
  union { u32 u; float f; } v; v.u = ((u32)h) << 16;
  return v.f;
}
__device__ __forceinline__ void gload16(const void* g, void* l) {
  __builtin_amdgcn_global_load_lds(
      (const __attribute__((address_space(1))) void*)g,
      (__attribute__((address_space(3))) void*)l, 16, 0, 0);
}
__device__ __forceinline__ f32x4 mfma16(bf16x8 a, bf16x8 b, f32x4 c) {
  return __builtin_amdgcn_mfma_f32_16x16x32_bf16(a, b, c, 0, 0, 0);
}

// ---------------- prep: LN + weight transposes (one launch) ----------------
// blocks [0,4096): LayerNorm row   [4096,7168): wqkv^T   [7168,8192): wout^T
__global__ __launch_bounds__(256) void prep_kernel(
    const float* __restrict__ x, const float* __restrict__ lw,
    const float* __restrict__ lb, const float* __restrict__ wqkv,
    const float* __restrict__ wout, u16* __restrict__ xn,
    u16* __restrict__ wqt, u16* __restrict__ wot) {
  __shared__ float tile[32][33];
  int blk = blockIdx.x, t = threadIdx.x;
  if (blk < 4096) {
    int r = blk;
    const float4* xr = (const float4*)(x + (size_t)r * DIM_);
    float4 v = xr[t];
    float s  = v.x + v.y + v.z + v.w;
    float s2 = v.x*v.x + v.y*v.y + v.z*v.z + v.w*v.w;
    #pragma unroll
    for (int off = 32; off >= 1; off >>= 1) {
      s  += __shfl_down(s, off);
      s2 += __shfl_down(s2, off);
    }
    int w = t >> 6, lane = t & 63;
    if (lane == 0) { tile[0][w] = s; tile[1][w] = s2; }
    __syncthreads();
    if (t == 0) {
      float S = tile[0][0]+tile[0][1]+tile[0][2]+tile[0][3];
      float S2 = tile[1][0]+tile[1][1]+tile[1][2]+tile[1][3];
      float mu = S * (1.0f/DIM_);
      float var = S2 * (1.0f/DIM_) - mu*mu;
      tile[2][0] = mu; tile[2][1] = rsqrtf(var + 1e-5f);
    }
    __syncthreads();
    float mu = tile[2][0], rs = tile[2][1];
    float4 wv = ((const float4*)lw)[t];
    float4 bv = ((const float4*)lb)[t];
    u32 lo = pkb((v.x-mu)*rs*wv.x + bv.x, (v.y-mu)*rs*wv.y + bv.y);
    u32 hi = pkb((v.z-mu)*rs*wv.z + bv.z, (v.w-mu)*rs*wv.w + bv.w);
    ((uint2*)xn)[(size_t)r*256 + t] = make_uint2(lo, hi);
  } else {
    const float* in; u16* outp; int R, C, c0, r0;
    if (blk < 7168) {
      int b2 = blk - 4096;
      in = wqkv; outp = wqt; R = 1024; C = 3072;
      c0 = (b2 % 96) * 32; r0 = (b2 / 96) * 32;
    } else {
      int b2 = blk - 7168;
      in = wout; outp = wot; R = 1024; C = 1024;
      c0 = (b2 & 31) * 32; r0 = (b2 >> 5) * 32;
    }
    int tx = t & 31, ty = t >> 5;
    #pragma unroll
    for (int i = 0; i < 4; i++)
      tile[ty + i*8][tx] = in[(size_t)(r0 + ty + i*8) * C + c0 + tx];
    __syncthreads();
    #pragma unroll
    for (int i = 0; i < 4; i++)
      outp[(size_t)(c0 + ty + i*8) * R + r0 + tx] = f2b(tile[tx][ty + i*8]);
  }
}

// ---------------- QKV GEMM (2-D grid) + T2 slot-swizzled LDS ---------------
// 128x128 tile, BK=32, single-buffer LDS + syncthreads.
// LDS rows are 64B (4 x 16B slots); slot' = slot ^ ((row>>1)&3) applied at
// BOTH the global source (stage) and the fragment read -> 2-way (free) banks.
// Scatter epilogue: q (bh,n,d), k (bh,n,d), v^T (bh,d,n).
__global__ __launch_bounds__(256) void gemm_qkv(
    const u16* __restrict__ A, const u16* __restrict__ Bt,
    u16* __restrict__ qo, u16* __restrict__ ko, u16* __restrict__ vo) {
  const int K = 1024;
  __shared__ __align__(16) u16 lA[128*32];
  __shared__ __align__(16) u16 lB[128*32];
  int tid = threadIdx.x;
  int lane = tid & 63;
  int w = tid >> 6, wm = w >> 1, wn = w & 1;
  int l15 = lane & 15, g = lane >> 4;
  int bm = blockIdx.x, bn = blockIdx.y;
  const f32x4 z = {0.f, 0.f, 0.f, 0.f};
  f32x4 acc[4][4];
  #pragma unroll
  for (int i = 0; i < 4; i++)
    #pragma unroll
    for (int j = 0; j < 4; j++)
      acc[i][j] = z;
  int sslot = (tid & 3) ^ ((tid >> 3) & 3);   // pre-swizzled source slot
  const u16* ag = A  + (size_t)(bm*128 + (tid>>2)) * K + sslot*8;
  const u16* bg = Bt + (size_t)(bn*128 + (tid>>2)) * K + sslot*8;
  u16* la = lA + tid*8;
  u16* lb = lB + tid*8;
  for (int k0 = 0; k0 < K; k0 += 32) {
    gload16(ag + k0,                la);
    gload16(ag + (size_t)64*K + k0, la + 2048);
    gload16(bg + k0,                lb);
    gload16(bg + (size_t)64*K + k0, lb + 2048);
    __syncthreads();
    bf16x8 af[4], bfr[4];
    #pragma unroll
    for (int mt = 0; mt < 4; mt++) {
      int R = wm*64 + mt*16 + l15;
      af[mt] = *(const bf16x8*)(lA + R*32 + (g ^ ((R >> 1) & 3))*8);
    }
    #pragma unroll
    for (int nt = 0; nt < 4; nt++) {
      int R = wn*64 + nt*16 + l15;
      bfr[nt] = *(const bf16x8*)(lB + R*32 + (g ^ ((R >> 1) & 3))*8);
    }
    __builtin_amdgcn_s_setprio(1);
    #pragma unroll
    for (int mt = 0; mt < 4; mt++)
      #pragma unroll
      for (int nt = 0; nt < 4; nt++)
        acc[mt][nt] = mfma16(af[mt], bfr[nt], acc[mt][nt]);
    __builtin_amdgcn_s_setprio(0);
    __syncthreads();
  }
  #pragma unroll
  for (int mt = 0; mt < 4; mt++) {
    #pragma unroll
    for (int nt = 0; nt < 4; nt++) {
      #pragma unroll
      for (int reg = 0; reg < 4; reg++) {
        int rr = bm*128 + wm*64 + mt*16 + g*4 + reg;
        int cc = bn*128 + wn*64 + nt*16 + l15;
        float val = acc[mt][nt][reg];
        int which = cc >> 10, inner = cc & 1023;
        int h = inner >> 6, dd = inner & 63;
        int b = rr >> 11, np = rr & 2047;
        int bh = b*HEADS_ + h;
        if (which == 0)      qo[((size_t)(bh*2048 + np))*64 + dd] = f2b(val);
        else if (which == 1) ko[((size_t)(bh*2048 + np))*64 + dd] = f2b(val);
        else                 vo[((size_t)(bh*64 + dd))*2048 + np] = f2b(val);
      }
    }
  }
}

// ---------------- RoPE in-place on k only (bh,n,64); coalesced -------------
// (Q rotation is fused into flash_attn's register Q-load.)
__global__ __launch_bounds__(256) void rope_k_kernel(u16* k) {
  int tid = blockIdx.x * 256 + threadIdx.x;   // 524288 = BH*N*8
  int row = tid >> 3, sub = tid & 7;
  int n = row & 2047;
  u32* kp = (u32*)(k + (size_t)row * 64 + sub * 8);
  uint4 uk = *(uint4*)kp;
  float c4[4], s4[4];
  #pragma unroll
  for (int j = 0; j < 4; j++) {
    int p = sub*4 + j;
    float freq = expf(-(2.0f * (float)p) * (9.210340371976184f / 64.0f));
    float ang = (float)n * freq;
    __sincosf(ang, &s4[j], &c4[j]);
  }
#define ROPE_K(u, c, s) { \
    float e = b2f((u16)(u)), o = b2f((u16)((u) >> 16)); \
    (u) = pkb(e*(c) - o*(s), o*(c) + e*(s)); }
  ROPE_K(uk.x, c4[0], s4[0]) ROPE_K(uk.y, c4[1], s4[1])
  ROPE_K(uk.z, c4[2], s4[2]) ROPE_K(uk.w, c4[3], s4[3])
#undef ROPE_K
  *(uint4*)kp = uk;
}

// ---------------- Output GEMM: 128x64 tile + T2 slot-swizzled LDS ----------
__global__ __launch_bounds__(256) void gemm_out(
    const u16* __restrict__ A, const u16* __restrict__ Bt,
    const float* __restrict__ bias, float* __restrict__ out) {
  const int K = 1024, N = 1024;
  __shared__ __align__(16) u16 lA[128*32];   // 8KB
  __shared__ __align__(16) u16 lB[64*32];    // 4KB
  int tid = threadIdx.x;
  int lane = tid & 63;
  int w = tid >> 6, wm = w >> 1, wn = w & 1;
  int l15 = lane & 15, g = lane >> 4;
  int bm = blockIdx.x, bn = blockIdx.y;
  const f32x4 z = {0.f, 0.f, 0.f, 0.f};
  f32x4 acc[4][2];
  #pragma unroll
  for (int i = 0; i < 4; i++)
    #pragma unroll
    for (int j = 0; j < 2; j++)
      acc[i][j] = z;
  int sslot = (tid & 3) ^ ((tid >> 3) & 3);   // pre-swizzled source slot
  const u16* ag = A  + (size_t)(bm*128 + (tid>>2)) * K + sslot*8;
  const u16* bg = Bt + (size_t)(bn*64 + (tid>>2)) * K + sslot*8;
  u16* la = lA + tid*8;
  u16* lb = lB + tid*8;
  for (int k0 = 0; k0 < K; k0 += 32) {
    gload16(ag + k0,                la);
    gload16(ag + (size_t)64*K + k0, la + 2048);
    gload16(bg + k0,                lb);
    __syncthreads();
    bf16x8 af[4], bfr[2];
    #pragma unroll
    for (int mt = 0; mt < 4; mt++) {
      int R = wm*64 + mt*16 + l15;
      af[mt] = *(const bf16x8*)(lA + R*32 + (g ^ ((R >> 1) & 3))*8);
    }
    #pragma unroll
    for (int nt = 0; nt < 2; nt++) {
      int R = wn*32 + nt*16 + l15;
      bfr[nt] = *(const bf16x8*)(lB + R*32 + (g ^ ((R >> 1) & 3))*8);
    }
    __builtin_amdgcn_s_setprio(1);
    #pragma unroll
    for (int mt = 0; mt < 4; mt++)
      #pragma unroll
      for (int nt = 0; nt < 2; nt++)
        acc[mt][nt] = mfma16(af[mt], bfr[nt], acc[mt][nt]);
    __builtin_amdgcn_s_setprio(0);
    __syncthreads();
  }
  #pragma unroll
  for (int mt = 0; mt < 4; mt++)
    #pragma unroll
    for (int nt = 0; nt < 2; nt++)
      #pragma unroll
      for (int reg = 0; reg < 4; reg++) {
        int rr = bm*128 + wm*64 + mt*16 + g*4 + reg;
        int cc = bn*64 + wn*32 + nt*16 + l15;
        out[(size_t)rr * N + cc] = acc[mt][nt][reg] + bias[cc];
      }
}

// ---------------- Flash attention (key-split, unrolled x3, MFMA denom) ------
// (R19, measured — unchanged)
__global__ __launch_bounds__(512, 4) void flash_attn(
    const u16* __restrict__ qbf, const u16* __restrict__ kbf,
    const u16* __restrict__ vt, u16* __restrict__ aout) {
  __shared__ __align__(16) char smem[49152];      // 3x8KB K | 3x8KB V; reused
  int tid = threadIdx.x;
  int w = tid >> 6, lane = tid & 63;
  int l15 = lane & 15, g = lane >> 4;
  int p = w & 3, rho = w >> 2;
  int lin = blockIdx.x;
  int nb = (lin & 7) * 64 + (lin >> 3);
  int bh = nb >> 4, qb = nb & 15;
  const f32x4 z = {0.f, 0.f, 0.f, 0.f};
  const u16* qrow_base = qbf + ((size_t)bh*2048 + qb*128 + p*32) * 64;
  const float qs = 0.125f * 1.4426950408889634f;
  bf16x8 Qf[2][2];
  #pragma unroll
  for (int qt = 0; qt < 2; qt++) {
    int n = qb*128 + p*32 + qt*16 + l15;
    #pragma unroll
    for (int dh = 0; dh < 2; dh++) {
      union { bf16x8 v; u32 u[4]; } f;
      f.v = *(const bf16x8*)(qrow_base + (qt*16 + l15)*64 + dh*32 + g*8);
      #pragma unroll
      for (int j = 0; j < 4; j++) {
        int pidx = dh*16 + g*4 + j;
        float freq = expf(-(2.0f * (float)pidx) * (9.210340371976184f / 64.0f));
        float sn, cn;
        __sincosf((float)n * freq, &sn, &cn);
        float e = b2f((u16)f.u[j]), o = b2f((u16)(f.u[j] >> 16));
        f.u[j] = pkb((e*cn - o*sn)*qs, (o*cn + e*sn)*qs);
      }
      Qf[qt][dh] = f.v;
    }
  }
  const char* kb = (const char*)(kbf + (size_t)bh * 2048 * 64);
  const char* vb = (const char*)(vt  + (size_t)bh * 64 * 2048);
  int srow = tid >> 3;                 // LDS row 0..63
  int soff = ((tid & 7) * 16) ^ ((srow & 7) << 4);   // inverse-swizzled source
  int sl = srow & 31;
  int ksrc = (srow & 32) | (((sl >> 2) & 3) << 3) | (((sl >> 4) & 1) << 2) | (sl & 3);
  const int swz = (l15 & 7) << 4;      // row-XOR read swizzle

  const size_t kgo = (size_t)ksrc * 128 + soff;     // K global, + t*8192
  const size_t vgo = (size_t)srow * 4096 + soff;    // V global, + t*128
  const int ldk = tid * 16;                          // K LDS dest, + buf*8192
  const int ldv = 24576 + tid * 16;                  // V LDS dest, + buf*8192
  int koff[2][2], voff[4];
  #pragma unroll
  for (int kt = 0; kt < 2; kt++)
    #pragma unroll
    for (int dh = 0; dh < 2; dh++)
      koff[kt][dh] = (rho*32 + kt*16 + l15)*128 + ((dh*64 + g*16) ^ swz);
  #pragma unroll
  for (int dt = 0; dt < 4; dt++)
    voff[dt] = 24576 + (dt*16 + l15)*128 + ((rho*64 + g*16) ^ swz);

  bf16x8 ones;
  #pragma unroll
  for (int i = 0; i < 8; i++) ones[i] = (__bf16)1.0f;

  f32x4 den[2] = {z, z};               // denominator accumulators (ones-MFMA)
  f32x4 o[4][2];                       // [dt][qt] partial O^T
  #pragma unroll
  for (int i = 0; i < 4; i++)
    #pragma unroll
    for (int j = 0; j < 2; j++)
      o[i][j] = z;

#define STAGE(T, BUF) { \
    gload16(kb + (size_t)(T)*8192 + kgo, smem + (BUF)*8192 + ldk); \
    gload16(vb + (size_t)(T)*128  + vgo, smem + (BUF)*8192 + ldv); }

#define FBODY(T, CUR, PFB, DOSTAGE, WM) { \
    if (DOSTAGE) STAGE((T) + 2, PFB) \
    f32x4 st[2][2]; \
    bf16x8 ka[2][2]; \
    _Pragma("unroll") \
    for (int kt = 0; kt < 2; kt++) \
      _Pragma("unroll") \
      for (int dh = 0; dh < 2; dh++) \
        ka[kt][dh] = *(const bf16x8*)(smem + (CUR)*8192 + koff[kt][dh]); \
    __builtin_amdgcn_s_setprio(1); \
    _Pragma("unroll") \
    for (int kt = 0; kt < 2; kt++) \
      _Pragma("unroll") \
      for (int qt = 0; qt < 2; qt++) { \
        f32x4 a = mfma16(ka[kt][0], Qf[qt][0], z); \
        st[kt][qt] = mfma16(ka[kt][1], Qf[qt][1], a); \
      } \
    __builtin_amdgcn_s_setprio(0); \
    _Pragma("unroll") \
    for (int kt = 0; kt < 2; kt++) \
      _Pragma("unroll") \
      for (int qt = 0; qt < 2; qt++) \
        _Pragma("unroll") \
        for (int r = 0; r < 4; r++) \
          st[kt][qt][r] = __builtin_amdgcn_exp2f(st[kt][qt][r]); \
    bf16x8 vf[4]; \
    _Pragma("unroll") \
    for (int dt = 0; dt < 4; dt++) \
      vf[dt] = *(const bf16x8*)(smem + (CUR)*8192 + voff[dt]); \
    __builtin_amdgcn_s_setprio(1); \
    _Pragma("unroll") \
    for (int qt = 0; qt < 2; qt++) { \
      union { u32 u[4]; bf16x8 v; } pf; \
      pf.u[0] = pkb(st[0][qt][0], st[0][qt][1]); \
      pf.u[1] = pkb(st[0][qt][2], st[0][qt][3]); \
      pf.u[2] = pkb(st[1][qt][0], st[1][qt][1]); \
      pf.u[3] = pkb(st[1][qt][2], st[1][qt][3]); \
      den[qt] = mfma16(ones, pf.v, den[qt]); \
      _Pragma("unroll") \
      for (int dt = 0; dt < 4; dt++) \
        o[dt][qt] = mfma16(vf[dt], pf.v, o[dt][qt]); \
    } \
    __builtin_amdgcn_s_setprio(0); \
    if ((WM) == 2) { \
      asm volatile("s_waitcnt vmcnt(2)" ::: "memory"); \
      __builtin_amdgcn_s_barrier(); \
    } else if ((WM) == 0) { \
      asm volatile("s_waitcnt vmcnt(0)" ::: "memory"); \
      __builtin_amdgcn_s_barrier(); \
    } }

  // prologue: fill buffers 0 and 1
  STAGE(0, 0)
  STAGE(1, 1)
  asm volatile("s_waitcnt vmcnt(2)" ::: "memory");
  __builtin_amdgcn_s_barrier();

  #pragma unroll 1
  for (int tb = 0; tb < 30; tb += 3) {
    FBODY(tb + 0, 0, 2, 1, 2)
    FBODY(tb + 1, 1, 0, 1, 2)
    FBODY(tb + 2, 2, 1, 1, 2)
  }
  FBODY(30, 0, 0, 0, 0)
  FBODY(31, 1, 0, 0, 3)
#undef STAGE
#undef FBODY

  float ls[2] = {den[0][0], den[1][0]};
  __syncthreads();   // all waves done with K/V buffers

  float* lspx = (float*)(smem + 32768);   // [p][qt*16+l15]
  if (rho == 1) {
    #pragma unroll
    for (int dt = 0; dt < 4; dt++)
      #pragma unroll
      for (int qt = 0; qt < 2; qt++) {
        int ql = qt*16 + l15;
        int off = p*8192 + ql*256 + ((dt*64 + g*16) ^ ((ql & 7) << 4));
        *(f32x4*)(smem + off) = o[dt][qt];
      }
    if (g == 0) {
      lspx[p*64 + l15]      = ls[0];
      lspx[p*64 + 16 + l15] = ls[1];
    }
  }
  __syncthreads();
  float rls[2] = {0.f, 0.f};
  if (rho == 0) {
    #pragma unroll
    for (int qt = 0; qt < 2; qt++)
      rls[qt] = 1.0f / (ls[qt] + lspx[p*64 + qt*16 + l15]);
    #pragma unroll
    for (int dt = 0; dt < 4; dt++)
      #pragma unroll
      for (int qt = 0; qt < 2; qt++) {
        int ql = qt*16 + l15;
        int off = p*8192 + ql*256 + ((dt*64 + g*16) ^ ((ql & 7) << 4));
        o[dt][qt] += *(const f32x4*)(smem + off);
      }
  }
  __syncthreads();   // ALL f32 reads complete before bf16 rows overwrite them
  if (rho == 0) {
    #pragma unroll
    for (int dt = 0; dt < 4; dt++)
      #pragma unroll
      for (int qt = 0; qt < 2; qt++) {
        int ql = qt*16 + l15;
        u32 w0 = pkb(o[dt][qt][0]*rls[qt], o[dt][qt][1]*rls[qt]);
        u32 w1 = pkb(o[dt][qt][2]*rls[qt], o[dt][qt][3]*rls[qt]);
        int d2 = dt*32 + g*8;   // byte offset of d run (d = dt*16+g*4)
        *(uint2*)(smem + p*8192 + ql*128 + (d2 ^ ((ql & 7) << 4))) =
            make_uint2(w0, w1);
      }
  }
  __syncthreads();
  int row = tid >> 2;
  int b = bh >> 4, h = bh & 15;
  int n = qb*128 + row;
  #pragma unroll
  for (int j = 0; j < 2; j++) {
    int slot = (tid & 3)*2 + j;
    uint4 rv = *(const uint4*)(smem + (row >> 5)*8192 + (row & 31)*128
                               + ((slot*16) ^ ((row & 7) << 4)));
    *(uint4*)(aout + ((size_t)(b*2048 + n))*1024 + h*64 + slot*8) = rv;
  }
}

extern "C" void kernel_launch(void* const* d_in, const int* in_sizes, int n_in,
                              void* d_out, int out_size, void* d_ws, size_t ws_size,
                              hipStream_t stream) {
  const float* x    = (const float*)d_in[0];
  const float* lw   = (const float*)d_in[1];
  const float* lb   = (const float*)d_in[2];
  const float* wqkv = (const float*)d_in[3];
  const float* wout = (const float*)d_in[4];
  const float* bout = (const float*)d_in[5];
  float* out = (float*)d_out;

  char* ws = (char*)d_ws;
  size_t off = 0;
  auto alloc = [&](size_t bytes) {
    char* p = ws + off;
    off += (bytes + 255) & ~(size_t)255;
    return p;
  };
  u16* xn   = (u16*)alloc((size_t)ROWS_*DIM_*2);
  u16* wqt  = (u16*)alloc((size_t)3072*1024*2);
  u16* wot  = (u16*)alloc((size_t)1024*1024*2);
  u16* qb   = (u16*)alloc((size_t)BH_*2048*64*2);
  u16* kb   = (u16*)alloc((size_t)BH_*2048*64*2);
  u16* vtb  = (u16*)alloc((size_t)BH_*2048*64*2);
  u16* aout = (u16*)alloc((size_t)ROWS_*1024*2);

  prep_kernel<<<8192, 256, 0, stream>>>(x, lw, lb, wqkv, wout, xn, wqt, wot);
  gemm_qkv<<<dim3(32, 24), 256, 0, stream>>>(xn, wqt, qb, kb, vtb);
  rope_k_kernel<<<2048, 256, 0, stream>>>(kb);
  flash_attn<<<512, 512, 0, stream>>>(qb, kb, vtb, aout);
  gemm_out<<<dim3(32, 16), 256, 0, stream>>>(aout, wot, bout, out);
}